// Round 1
// baseline (362.811 us; speedup 1.0000x reference)
//
#include <hip/hip_runtime.h>
#include <math.h>
#include <stdint.h>

#define BS   16
#define CH   256
#define NPIX 16384        // 128*128
#define TOPK 12
#define WPB  (NPIX / 64)  // 256 uint64 mask words per batch

typedef float nfloat4 __attribute__((ext_vector_type(4)));

// ---------------------------------------------------------------------------
// Kernel A: softmax over the 2 logit channels -> fg/bg threshold bits, packed
// via __ballot into one uint64 per 64 pixels. Grid: BS*(NPIX/256) = 1024
// blocks of 256. Unchanged from previous version (~8 us, coalesced).
// ---------------------------------------------------------------------------
__global__ __launch_bounds__(256) void mask_kernel(
    const float* __restrict__ outp,   // (BS, 2, NPIX)
    const float* __restrict__ tau,    // scalar
    uint64_t* __restrict__ mfg,       // (BS, WPB) fg bits
    uint64_t* __restrict__ mbg)       // (BS, WPB) bg bits
{
    int b = blockIdx.x >> 6;                       // 64 blocks per batch
    int n = ((blockIdx.x & 63) << 8) + threadIdx.x;

    float t = tau[0];
    float fthres = 1.0f / (1.0f + expf(-t));       // sigmoid(tau)
    float bthres = 1.0f - fthres;

    float o0 = outp[((size_t)b * 2    ) * NPIX + n];
    float o1 = outp[((size_t)b * 2 + 1) * NPIX + n];
    float m  = fmaxf(o0, o1);
    float e0 = expf(o0 - m);
    float e1 = expf(o1 - m);
    float inv = 1.0f / (e0 + e1);

    int fg = (e1 * inv) > fthres;   // pred_fg > fg_thres
    int bg = (e0 * inv) > bthres;   // pred_bg > bg_thres

    uint64_t bf = __ballot(fg);
    uint64_t bb = __ballot(bg);
    if ((threadIdx.x & 63) == 0) {
        int w = n >> 6;
        mfg[b * WPB + w] = bf;
        mbg[b * WPB + w] = bb;
    }
}

// ---------------------------------------------------------------------------
// Kernel B (HBM-bound): 2048 blocks of 256; each block streams TWO contiguous
// channel rows (128 KB) of one batch. 8 blocks/CU = 32 waves/CU — the m13
// max-BW shape. Mask bits staged once in LDS for both rows; accumulation is
// branchless ternary selects (v_cndmask). Popcounts of the mask words give
// cnt for free, so the mean (sum / max(cnt,1)) is written directly.
// ---------------------------------------------------------------------------
__global__ __launch_bounds__(256) void sum_kernel(
    const float* __restrict__ feat,           // (BS, CH, NPIX)
    const uint64_t* __restrict__ mfg,
    const uint64_t* __restrict__ mbg,
    float* __restrict__ dout)
{
    int b  = blockIdx.x >> 7;                 // 128 blocks per batch
    int c0 = (blockIdx.x & 127) << 1;         // rows c0, c0+1

    __shared__ uint64_t lf[WPB], lb[WPB];
    __shared__ int scnt[8];

    uint64_t wf = mfg[b * WPB + threadIdx.x];
    uint64_t wb = mbg[b * WPB + threadIdx.x];
    lf[threadIdx.x] = wf;
    lb[threadIdx.x] = wb;

    // fg/bg pixel counts (popcount of the words we just loaded)
    int pf = (int)__popcll(wf), pb = (int)__popcll(wb);
    #pragma unroll
    for (int off = 32; off > 0; off >>= 1) {
        pf += __shfl_down(pf, off);
        pb += __shfl_down(pb, off);
    }
    int lane = threadIdx.x & 63, wid = threadIdx.x >> 6;
    if (lane == 0) { scnt[wid] = pf; scnt[4 + wid] = pb; }
    __syncthreads();
    int cfg = scnt[0] + scnt[1] + scnt[2] + scnt[3];
    int cbg = scnt[4] + scnt[5] + scnt[6] + scnt[7];

    const nfloat4* f0 = (const nfloat4*)(feat + (((size_t)b * CH + c0) << 14));
    const nfloat4* f1 = f0 + (NPIX / 4);

    float s0f = 0.f, s0b = 0.f, s1f = 0.f, s1b = 0.f;
    #pragma unroll
    for (int i = 0; i < 16; ++i) {
        int idx = i * 256 + threadIdx.x;
        nfloat4 a = f0[idx];
        nfloat4 d = f1[idx];
        int p = idx << 2;                                  // first pixel of 4
        unsigned fb = (unsigned)(lf[p >> 6] >> (p & 63)) & 0xF;
        unsigned bb = (unsigned)(lb[p >> 6] >> (p & 63)) & 0xF;
        s0f += (fb & 1) ? a.x : 0.f;
        s0f += (fb & 2) ? a.y : 0.f;
        s0f += (fb & 4) ? a.z : 0.f;
        s0f += (fb & 8) ? a.w : 0.f;
        s0b += (bb & 1) ? a.x : 0.f;
        s0b += (bb & 2) ? a.y : 0.f;
        s0b += (bb & 4) ? a.z : 0.f;
        s0b += (bb & 8) ? a.w : 0.f;
        s1f += (fb & 1) ? d.x : 0.f;
        s1f += (fb & 2) ? d.y : 0.f;
        s1f += (fb & 4) ? d.z : 0.f;
        s1f += (fb & 8) ? d.w : 0.f;
        s1b += (bb & 1) ? d.x : 0.f;
        s1b += (bb & 2) ? d.y : 0.f;
        s1b += (bb & 4) ? d.z : 0.f;
        s1b += (bb & 8) ? d.w : 0.f;
    }

    // 64-lane wave reduction, then cross-wave via LDS
    #pragma unroll
    for (int off = 32; off > 0; off >>= 1) {
        s0f += __shfl_down(s0f, off);
        s0b += __shfl_down(s0b, off);
        s1f += __shfl_down(s1f, off);
        s1b += __shfl_down(s1b, off);
    }
    __shared__ float r0[4], r1[4], r2[4], r3[4];
    if (lane == 0) { r0[wid] = s0f; r1[wid] = s0b; r2[wid] = s1f; r3[wid] = s1b; }
    __syncthreads();
    if (threadIdx.x == 0) {
        float cf = (float)(cfg > 0 ? cfg : 1);
        float cb = (float)(cbg > 0 ? cbg : 1);
        float a0 = r0[0] + r0[1] + r0[2] + r0[3];   // fg sum, row c0
        float a1 = r1[0] + r1[1] + r1[2] + r1[3];   // bg sum, row c0
        float a2 = r2[0] + r2[1] + r2[2] + r2[3];   // fg sum, row c0+1
        float a3 = r3[0] + r3[1] + r3[2] + r3[3];   // bg sum, row c0+1
        dout[b * CH + c0]               = a0 / cf;  // masked mean (ref: sum/max(cnt,1))
        dout[b * CH + c0 + 1]           = a2 / cf;
        dout[BS * CH + b * CH + c0]     = a1 / cb;
        dout[BS * CH + b * CH + c0 + 1] = a3 / cb;
    }
}

// ---------------------------------------------------------------------------
// Kernel C: fallback only. One block per (b, which): 2*BS = 32 blocks.
// cnt>0 (common): sum_kernel already wrote the mean -> early return.
// cnt==0 (rare, block-uniform): exact top-12 (desc value, asc index — matches
// jax.lax.top_k) of the softmax prob, then per-channel gather-mean overwrite.
// ---------------------------------------------------------------------------
__global__ __launch_bounds__(256) void finalize_kernel(
    const float* __restrict__ feat,
    const float* __restrict__ outp,
    const uint64_t* __restrict__ mfg,
    const uint64_t* __restrict__ mbg,
    float* __restrict__ dout)
{
    int b     = blockIdx.x >> 1;
    int which = blockIdx.x & 1;   // 0 = fg, 1 = bg
    const uint64_t* mw = which ? mbg : mfg;
    float* o = dout + (size_t)which * BS * CH + (size_t)b * CH;

    int pc = (int)__popcll(mw[b * WPB + threadIdx.x]);
    #pragma unroll
    for (int off = 32; off > 0; off >>= 1) pc += __shfl_down(pc, off);
    __shared__ int sw[4];
    if ((threadIdx.x & 63) == 0) sw[threadIdx.x >> 6] = pc;
    __syncthreads();
    int cnt = sw[0] + sw[1] + sw[2] + sw[3];

    if (cnt > 0) return;   // mean already written by sum_kernel

    // ---- top-k fallback (block-uniform branch) ----
    __shared__ int   sel[TOPK];
    __shared__ float shv[256];
    __shared__ int   shi[256];

    const float* o0p = outp + ((size_t)b * 2) * NPIX;
    const float* o1p = o0p + NPIX;

    for (int k = 0; k < TOPK; ++k) {
        float bestv = -INFINITY;
        int   besti = 0x7fffffff;
        for (int n = threadIdx.x; n < NPIX; n += 256) {
            bool skip = false;
            for (int j = 0; j < k; ++j) if (sel[j] == n) { skip = true; break; }
            if (skip) continue;
            float a0 = o0p[n], a1 = o1p[n];
            float m  = fmaxf(a0, a1);
            float e0 = expf(a0 - m);
            float e1 = expf(a1 - m);
            float p  = (which == 0 ? e1 : e0) / (e0 + e1);
            if (p > bestv || (p == bestv && n < besti)) { bestv = p; besti = n; }
        }
        shv[threadIdx.x] = bestv;
        shi[threadIdx.x] = besti;
        __syncthreads();
        for (int off = 128; off > 0; off >>= 1) {
            if (threadIdx.x < off) {
                float v2 = shv[threadIdx.x + off];
                int   i2 = shi[threadIdx.x + off];
                if (v2 > shv[threadIdx.x] ||
                    (v2 == shv[threadIdx.x] && i2 < shi[threadIdx.x])) {
                    shv[threadIdx.x] = v2;
                    shi[threadIdx.x] = i2;
                }
            }
            __syncthreads();
        }
        if (threadIdx.x == 0) sel[k] = shi[0];
        __syncthreads();
    }

    const float* fb = feat + ((size_t)b * CH + threadIdx.x) * (size_t)NPIX;
    float s = 0.0f;
    for (int j = 0; j < TOPK; ++j) s += fb[sel[j]];
    o[threadIdx.x] = s / (float)TOPK;
}

extern "C" void kernel_launch(void* const* d_in, const int* in_sizes, int n_in,
                              void* d_out, int out_size, void* d_ws, size_t ws_size,
                              hipStream_t stream) {
    const float* feat = (const float*)d_in[0];  // (16,256,128,128) fp32
    const float* outp = (const float*)d_in[1];  // (16,2,128,128)  fp32
    const float* tau  = (const float*)d_in[2];  // scalar fp32
    float* dout = (float*)d_out;                // 2 * 16*256 fp32

    uint64_t* mfg = (uint64_t*)d_ws;                         // 32 KB
    uint64_t* mbg = (uint64_t*)((char*)d_ws + (size_t)BS * WPB * 8);

    mask_kernel<<<BS * (NPIX / 256), 256, 0, stream>>>(outp, tau, mfg, mbg);
    sum_kernel<<<(BS * CH) / 2, 256, 0, stream>>>(feat, mfg, mbg, dout);
    finalize_kernel<<<2 * BS, 256, 0, stream>>>(feat, outp, mfg, mbg, dout);
}

// Round 2
// 358.129 us; speedup vs baseline: 1.0131x; 1.0131x over previous
//
#include <hip/hip_runtime.h>
#include <math.h>
#include <stdint.h>

#define BS   16
#define CH   256
#define NPIX 16384        // 128*128
#define TOPK 12
#define WPB  (NPIX / 64)  // 256 uint64 mask words per batch
#define NBLK 2048         // sum_kernel grid: 8 blocks/CU, m13 shape
#define NITER 32          // 16M nfloat4 / (2048 blocks * 256 thr)

typedef float nfloat4 __attribute__((ext_vector_type(4)));

// ---------------------------------------------------------------------------
// Kernel A: softmax over the 2 logit channels -> fg/bg threshold bits, packed
// via __ballot into one uint64 per 64 pixels. Grid: BS*(NPIX/256) = 1024
// blocks of 256. Unchanged (proven, ~5 us).
// ---------------------------------------------------------------------------
__global__ __launch_bounds__(256) void mask_kernel(
    const float* __restrict__ outp,   // (BS, 2, NPIX)
    const float* __restrict__ tau,    // scalar
    uint64_t* __restrict__ mfg,       // (BS, WPB) fg bits
    uint64_t* __restrict__ mbg)       // (BS, WPB) bg bits
{
    int b = blockIdx.x >> 6;                       // 64 blocks per batch
    int n = ((blockIdx.x & 63) << 8) + threadIdx.x;

    float t = tau[0];
    float fthres = 1.0f / (1.0f + expf(-t));       // sigmoid(tau)
    float bthres = 1.0f - fthres;

    float o0 = outp[((size_t)b * 2    ) * NPIX + n];
    float o1 = outp[((size_t)b * 2 + 1) * NPIX + n];
    float m  = fmaxf(o0, o1);
    float e0 = expf(o0 - m);
    float e1 = expf(o1 - m);
    float inv = 1.0f / (e0 + e1);

    int fg = (e1 * inv) > fthres;   // pred_fg > fg_thres
    int bg = (e0 * inv) > bthres;   // pred_bg > bg_thres

    uint64_t bf = __ballot(fg);
    uint64_t bb = __ballot(bg);
    if ((threadIdx.x & 63) == 0) {
        int w = n >> 6;
        mfg[b * WPB + w] = bf;
        mbg[b * WPB + w] = bb;
    }
}

// ---------------------------------------------------------------------------
// Kernel B: flat grid-stride masked sum — the m13 "moving window" access
// pattern. At iteration k, ALL resident blocks read one contiguous 8 MiB
// window of feat (block blk covers 4 KB at offset k*8MiB + blk*4KiB), which
// sweeps memory monotonically -> DRAM row-buffer friendly, unlike the old
// block-owns-a-64KB-region shape (2048 scattered streams, measured ~1.7 TB/s).
// A block's 4 KB per iteration lies inside exactly ONE (b,c) row, so per
// iteration: 8 branchless masked adds, 6-level wave shfl reduce, lane0 writes
// one per-(row, slot) partial. Atomic-free: each (row, slot) written once.
// Masks read straight from global (32 KB, L2-resident; 4-lane dedup).
// ---------------------------------------------------------------------------
__global__ __launch_bounds__(256) void sum_kernel(
    const float* __restrict__ feat,           // (BS, CH, NPIX) = 16M nfloat4
    const uint64_t* __restrict__ mfg,
    const uint64_t* __restrict__ mbg,
    float* __restrict__ scratch)              // fg: [4096][64]; bg at +4096*64
{
    const int tid  = threadIdx.x;
    const int lane = tid & 63;
    const int wid  = tid >> 6;
    const int slot = ((blockIdx.x & 15) << 2) | wid;   // 16 blocks x 4 waves per row

    const nfloat4* fp = (const nfloat4*)feat;

    #pragma unroll 4
    for (int k = 0; k < NITER; ++k) {
        unsigned i = ((unsigned)(k * NBLK + blockIdx.x) << 8) | (unsigned)tid; // nfloat4 idx
        nfloat4 f = __builtin_nontemporal_load(&fp[i]);

        unsigned b    = i >> 20;                // batch  (row = i>>12, b = row>>8)
        unsigned word = (i & 4095u) >> 4;       // mask word within batch
        unsigned midx = (b << 8) | word;
        uint64_t wf = mfg[midx];
        uint64_t wb = mbg[midx];
        unsigned sh = (i & 15u) << 2;           // bit position of first pixel
        unsigned fb = (unsigned)(wf >> sh) & 0xF;
        unsigned bb = (unsigned)(wb >> sh) & 0xF;

        float sfg = 0.f, sbg = 0.f;
        sfg += (fb & 1) ? f.x : 0.f;
        sfg += (fb & 2) ? f.y : 0.f;
        sfg += (fb & 4) ? f.z : 0.f;
        sfg += (fb & 8) ? f.w : 0.f;
        sbg += (bb & 1) ? f.x : 0.f;
        sbg += (bb & 2) ? f.y : 0.f;
        sbg += (bb & 4) ? f.z : 0.f;
        sbg += (bb & 8) ? f.w : 0.f;

        #pragma unroll
        for (int off = 32; off > 0; off >>= 1) {
            sfg += __shfl_down(sfg, off);
            sbg += __shfl_down(sbg, off);
        }
        if (lane == 0) {
            unsigned row = i >> 12;             // global row id = b*CH + c
            scratch[(row << 6) | slot]                 = sfg;
            scratch[(4096u << 6) + ((row << 6) | slot)] = sbg;
        }
    }
}

// ---------------------------------------------------------------------------
// Kernel B2: reduce the 64 partials per (which,row) into raw sums in dout.
// 8192 sums of 64 floats; one wave per sum, coalesced 256 B reads, 6 shfl.
// Grid: 128 blocks x 256 -> 512 waves, 16 sums each. ~3 us.
// ---------------------------------------------------------------------------
__global__ __launch_bounds__(256) void reduce_kernel(
    const float* __restrict__ scratch,
    float* __restrict__ dout)
{
    int lane = threadIdx.x & 63;
    int wave = (blockIdx.x << 2) | (threadIdx.x >> 6);  // 0..511
    for (int v = wave; v < 2 * 4096; v += 512) {
        float s = scratch[((unsigned)v << 6) | lane];
        #pragma unroll
        for (int off = 32; off > 0; off >>= 1) s += __shfl_down(s, off);
        // v = which*4096 + (b*CH + c)  ==  dout layout directly
        if (lane == 0) dout[v] = s;
    }
}

// ---------------------------------------------------------------------------
// Kernel C: finalize (round-0 proven version). One block per (b, which).
// cnt from popcount of the packed mask. cnt>0: divide raw sums in place.
// cnt==0 (rare, block-uniform): exact top-12 (desc value, asc index — matches
// jax.lax.top_k) of the softmax prob, then per-channel gather-mean.
// ---------------------------------------------------------------------------
__global__ __launch_bounds__(256) void finalize_kernel(
    const float* __restrict__ feat,
    const float* __restrict__ outp,
    const uint64_t* __restrict__ mfg,
    const uint64_t* __restrict__ mbg,
    float* __restrict__ dout)
{
    int b     = blockIdx.x >> 1;
    int which = blockIdx.x & 1;   // 0 = fg, 1 = bg
    const uint64_t* mw = which ? mbg : mfg;
    float* o = dout + (size_t)which * BS * CH + (size_t)b * CH;

    int pc = (int)__popcll(mw[b * WPB + threadIdx.x]);
    #pragma unroll
    for (int off = 32; off > 0; off >>= 1) pc += __shfl_down(pc, off);
    __shared__ int sw[4];
    if ((threadIdx.x & 63) == 0) sw[threadIdx.x >> 6] = pc;
    __syncthreads();
    int cnt = sw[0] + sw[1] + sw[2] + sw[3];

    if (cnt > 0) {
        o[threadIdx.x] = o[threadIdx.x] / (float)cnt;
        return;
    }

    // ---- top-k fallback (block-uniform branch) ----
    __shared__ int   sel[TOPK];
    __shared__ float shv[256];
    __shared__ int   shi[256];

    const float* o0p = outp + ((size_t)b * 2) * NPIX;
    const float* o1p = o0p + NPIX;

    for (int k = 0; k < TOPK; ++k) {
        float bestv = -INFINITY;
        int   besti = 0x7fffffff;
        for (int n = threadIdx.x; n < NPIX; n += 256) {
            bool skip = false;
            for (int j = 0; j < k; ++j) if (sel[j] == n) { skip = true; break; }
            if (skip) continue;
            float a0 = o0p[n], a1 = o1p[n];
            float m  = fmaxf(a0, a1);
            float e0 = expf(a0 - m);
            float e1 = expf(a1 - m);
            float p  = (which == 0 ? e1 : e0) / (e0 + e1);
            if (p > bestv || (p == bestv && n < besti)) { bestv = p; besti = n; }
        }
        shv[threadIdx.x] = bestv;
        shi[threadIdx.x] = besti;
        __syncthreads();
        for (int off = 128; off > 0; off >>= 1) {
            if (threadIdx.x < off) {
                float v2 = shv[threadIdx.x + off];
                int   i2 = shi[threadIdx.x + off];
                if (v2 > shv[threadIdx.x] ||
                    (v2 == shv[threadIdx.x] && i2 < shi[threadIdx.x])) {
                    shv[threadIdx.x] = v2;
                    shi[threadIdx.x] = i2;
                }
            }
            __syncthreads();
        }
        if (threadIdx.x == 0) sel[k] = shi[0];
        __syncthreads();
    }

    const float* fb = feat + ((size_t)b * CH + threadIdx.x) * (size_t)NPIX;
    float s = 0.0f;
    for (int j = 0; j < TOPK; ++j) s += fb[sel[j]];
    o[threadIdx.x] = s / (float)TOPK;
}

extern "C" void kernel_launch(void* const* d_in, const int* in_sizes, int n_in,
                              void* d_out, int out_size, void* d_ws, size_t ws_size,
                              hipStream_t stream) {
    const float* feat = (const float*)d_in[0];  // (16,256,128,128) fp32
    const float* outp = (const float*)d_in[1];  // (16,2,128,128)  fp32
    const float* tau  = (const float*)d_in[2];  // scalar fp32
    float* dout = (float*)d_out;                // 2 * 16*256 fp32

    uint64_t* mfg = (uint64_t*)d_ws;                                  // 32 KB
    uint64_t* mbg = (uint64_t*)((char*)d_ws + (size_t)BS * WPB * 8);  // 32 KB
    float* scratch = (float*)((char*)d_ws + 2 * (size_t)BS * WPB * 8); // 2 MiB

    mask_kernel<<<BS * (NPIX / 256), 256, 0, stream>>>(outp, tau, mfg, mbg);
    sum_kernel<<<NBLK, 256, 0, stream>>>(feat, mfg, mbg, scratch);
    reduce_kernel<<<128, 256, 0, stream>>>(scratch, dout);
    finalize_kernel<<<2 * BS, 256, 0, stream>>>(feat, outp, mfg, mbg, dout);
}